// Round 16
// baseline (3845.470 us; speedup 1.0000x reference)
//
#include <hip/hip_runtime.h>

typedef __attribute__((ext_vector_type(8))) short short8;
typedef __attribute__((ext_vector_type(4))) float f32x4;
typedef __attribute__((ext_vector_type(4))) int   i32x4;

#define MFMA(a,b,c)  __builtin_amdgcn_mfma_f32_16x16x32_bf16(a,b,c,0,0,0)
#define MFMAI(a,b,c) __builtin_amdgcn_mfma_i32_16x16x64_i8(a,b,c,0,0,0)

// Problem dims
#define S_LEN 128
#define IN_D  8
#define HID   512
#define NL    3
#define H8STR 528       // i8 h row stride (bytes)
#define LOG2E  1.4426950408889634f
#define LOG2E2 2.8853901617779268f
#define WKL_STRIDE ((size_t)(32 * 8 * 3 * 64 * 16))   // per-layer Whh bytes
#define NTC_STRIDE ((size_t)(8 * 3 * 64 * 16))        // per-ntile Whh bytes (24576)

// ws layout (bytes)
#define OFF_WI8  0                       // [3][32nt][8kk][3g][64][16B] i8 = 2,359,296
#define OFF_WIH  (2359296)               // [3][32][3][64][8] bf16        =   294,912
#define OFF_SW   (2359296 + 294912)      // 4608 f32 dequant scales       =    18,432
#define OFF_SWI  (OFF_SW + 18432)        // 4608 f32 inv scales           =    18,432

__device__ __forceinline__ unsigned short f2bf(float f){
  unsigned u = __float_as_uint(f);
  u += 0x7FFFu + ((u >> 16) & 1u);
  return (unsigned short)(u >> 16);
}
__device__ __forceinline__ float fexp2(float x){ return __builtin_amdgcn_exp2f(x); }
__device__ __forceinline__ float frcp(float x){ return __builtin_amdgcn_rcpf(x); }

// Per-row absmax scales for Whh
__global__ void prep_scale(const float* __restrict__ Whh,
                           float* __restrict__ sw, float* __restrict__ swi){
  int row = blockIdx.x * 4 + (threadIdx.x >> 6);
  int lane = threadIdx.x & 63;
  const float* src = Whh + (size_t)row * 512;
  float m = 0.f;
#pragma unroll
  for (int i = 0; i < 8; ++i) m = fmaxf(m, fabsf(src[lane + i * 64]));
#pragma unroll
  for (int off = 32; off; off >>= 1) m = fmaxf(m, (float)__shfl_xor(m, off));
  m = fmaxf(m, 1e-20f);
  if (lane == 0){ sw[row] = m / 127.f; swi[row] = 127.f / m; }
}

// Quantize+pack Whh -> i8 A-fragments (K=64), gate-interleaved per kk
__global__ void prep_wi8(const float* __restrict__ Whh, const float* __restrict__ swi,
                         unsigned char* __restrict__ Wp8){
  int gid = blockIdx.x * 256 + threadIdx.x;     // 147456 total
  int lane = gid & 63;
  int r = gid >> 6;
  int g  = r % 3;  r /= 3;
  int kk = r & 7;  r >>= 3;
  int nt = r & 31;
  int l  = r >> 5;
  int row = l * 1536 + g * 512 + nt * 16 + (lane & 15);
  int k0  = kk * 64 + (lane >> 4) * 16;
  const float* src = Whh + (size_t)row * 512 + k0;
  float si = swi[row];
  uint4 v = {0,0,0,0};
  unsigned w[4] = {0,0,0,0};
#pragma unroll
  for (int j = 0; j < 16; ++j){
    int q = (int)rintf(src[j] * si);
    q = q > 127 ? 127 : (q < -127 ? -127 : q);
    w[j >> 2] |= ((unsigned)(q & 0xFF)) << ((j & 3) * 8);
  }
  v.x = w[0]; v.y = w[1]; v.z = w[2]; v.w = w[3];
  *(uint4*)(Wp8 + (size_t)gid * 16) = v;
}

// Pack Wih -> zero-padded (K=8 of 32) bf16 A-fragments, prescaled to exp2 domain
__global__ void prep_wih(const float* __restrict__ Wih, unsigned short* __restrict__ Wip){
  int gid = blockIdx.x * 256 + threadIdx.x;     // 18432 total
  int lane = gid & 63;
  int r = gid >> 6;
  int g  = r % 3;  r /= 3;
  int nt = r & 31;
  int l  = r >> 5;
  float scl = (g == 2) ? LOG2E2 : LOG2E;
  unsigned short t[8] = {0,0,0,0,0,0,0,0};
  if ((lane >> 4) == 0){
    int n = g * 512 + nt * 16 + (lane & 15);
    const float* src = Wih + ((size_t)l * 1536 + n) * 8;
#pragma unroll
    for (int j = 0; j < 8; ++j) t[j] = f2bf(src[j] * scl);
  }
  uint4 v;
  v.x = t[0] | ((unsigned)t[1] << 16);
  v.y = t[2] | ((unsigned)t[3] << 16);
  v.z = t[4] | ((unsigned)t[5] << 16);
  v.w = t[6] | ((unsigned)t[7] << 16);
  *(uint4*)(Wip + (size_t)gid * 8) = v;
}

// Main: 128 blocks x 1024 threads (16 waves), 1 block/CU. NO inter-block exchange:
// block owns 32 batch rows x ALL 512 cols (wave = 2 ntiles, processed sequentially so
// live accumulators fit the 64-VGPR budget). Per-XCD L2 weight stream identical to the
// pair-split (12 MB/step), but zero flags/mailbox/UC/vmcnt-drain overhead: exactly ONE
// intra-block barrier per cell-layer. Weight pipeline: 2 named slots, 16-fragment
// sequence (nt0 kk0..7, nt1 kk0..7), cross-step prefetch, never drained.
__global__ __launch_bounds__(1024) void gru_main(
    const float* __restrict__ x,
    const unsigned char* __restrict__ Wp8,
    const unsigned short* __restrict__ Wip,
    const float* __restrict__ bih,
    const float* __restrict__ bhh,
    const float* __restrict__ sw,
    float* __restrict__ out)
{
  __shared__ __align__(16) unsigned char  hB8[2][32 * H8STR]; // 33,792 B
  __shared__ __align__(16) unsigned short xpack[2][1024];     //  4,096 B
  __shared__ __align__(16) float sBrz[3 * 1024];              // 12,288 B
  __shared__ __align__(16) float sBni[3 * 512];               //  6,144 B
  __shared__ __align__(16) float sBnh[3 * 512];               //  6,144 B
  __shared__ __align__(16) float sK[4608];                    // 18,432 B
  __shared__ int   pad[1024];                                 //  4,096 B -> 84,992: 1 blk/CU

  const int tid  = threadIdx.x;
  const int wv   = tid >> 6;
  const int lane = tid & 63;
  const int l15  = lane & 15;
  const int l4   = lane >> 4;

  const int bid   = blockIdx.x;          // 0..127
  const int b0    = bid * 32;
  const int colv0 = wv * 32 + l4 * 4;    // lane's first out-col, ntile 0
  const int colv1 = colv0 + 16;          // ntile 1
  const int ntc0  = wv * 2;              // first 16-col tile index

  // pad liveness guard (x is never 1/2) — prevents LDS DCE (R8 lesson)
  if ((size_t)x == 1) pad[tid] = tid;

  for (int i = tid; i < 2 * 32 * H8STR / 4; i += 1024) ((unsigned*)hB8)[i] = 0;
  for (int i = tid; i < 3072; i += 1024){
    int l = i >> 10, c = i & 1023;
    sBrz[i] = (bih[l * 1536 + c] + bhh[l * 1536 + c]) * LOG2E;
  }
  for (int i = tid; i < 1536; i += 1024){
    int l = i >> 9, c = i & 511;
    sBni[i] = bih[l * 1536 + 1024 + c] * LOG2E2;
    sBnh[i] = bhh[l * 1536 + 1024 + c] * LOG2E2;
  }
  for (int i = tid; i < 4608; i += 1024){
    int g = (i % 1536) >> 9;
    sK[i] = sw[i] * (1.f / 127.f) * (g == 2 ? LOG2E2 : LOG2E);
  }

  float hreg[2][2][4];   // [ntile][batch-frag][outcol q] — all indices compile-time
#pragma unroll
  for (int nt = 0; nt < 2; ++nt)
#pragma unroll
    for (int nf = 0; nf < 2; ++nf)
#pragma unroll
      for (int qq = 0; qq < 4; ++qq) hreg[nt][nf][qq] = 0.f;

  // xpack writer: entry (m*64+ln)*8+j = x[b0+m*16+(ln&15)][j] for ln<16 else 0
  const int xl = (tid >> 3) & 63;
  const size_t xbase = ((size_t)(b0 + (tid >> 9) * 16 + (xl & 15))) * (S_LEN * IN_D) + (tid & 7);
  const int xvalid = (xl < 16);
  { float xv = xvalid ? x[xbase] : 0.f; xpack[0][tid] = f2bf(xv); }
  __syncthreads();

  const int boff0 = l15 * H8STR + l4 * 16;        // h B-frag nf=0 (batch 0..15), bytes
  const int boff1 = boff0 + 16 * H8STR;           // nf=1 (batch 16..31)

  const unsigned char*  wklB = Wp8 + (size_t)ntc0 * NTC_STRIDE + (size_t)lane * 16;
  const unsigned short* wilB = Wip + (size_t)ntc0 * 3 * 512 + (size_t)lane * 8;

  // fragment sequence i=0..15: i<8 -> ntile0 kk=i ; i>=8 -> ntile1 kk=i-8
#define FPTR(W0, i) ((i) < 8 ? (W0) + (size_t)(i) * 3072 \
                             : (W0) + NTC_STRIDE + (size_t)((i) - 8) * 3072)
#define WLD(S, P) { const unsigned char* w_ = (P); \
    wR##S = *(const i32x4*)(w_); \
    wZ##S = *(const i32x4*)(w_ + 1024); \
    wN##S = *(const i32x4*)(w_ + 2048); }
#define CONS(S, i) { \
    i32x4 hb0 = *(const i32x4*)(hb8c + boff0 + ((i) & 7) * 64); \
    i32x4 hb1 = *(const i32x4*)(hb8c + boff1 + ((i) & 7) * 64); \
    aR[0] = MFMAI(wR##S, hb0, aR[0]);  aR[1] = MFMAI(wR##S, hb1, aR[1]); \
    aZ[0] = MFMAI(wZ##S, hb0, aZ[0]);  aZ[1] = MFMAI(wZ##S, hb1, aZ[1]); \
    aN[0] = MFMAI(wN##S, hb0, aN[0]);  aN[1] = MFMAI(wN##S, hb1, aN[1]); }

  // loop-carried weight pipeline slots; prologue fill for (t=0,l=0) seq 0,1
  i32x4 wRa, wZa, wNa, wRb, wZb, wNb;
  WLD(a, FPTR(wklB, 0))  WLD(b, FPTR(wklB, 1))

  int cur = 0;
#pragma unroll 1
  for (int t = 0; t < S_LEN; ++t){
    const unsigned short* xp = &xpack[t & 1][0];
#pragma unroll 1
    for (int l = 0; l < NL; ++l){
      const int last = (t == S_LEN - 1) && (l == NL - 1);
      const unsigned char* hb8c = hB8[cur];
      unsigned char*       hb8n = hB8[cur ^ 1];
      const unsigned char*  wkl = wklB + (size_t)l * WKL_STRIDE;
      const unsigned short* wil = wilB + (size_t)l * (32 * 3 * 512);

      // x fragments (shared by both ntiles' gi)
      short8 xb0 = *(const short8*)(xp + lane * 8);
      short8 xb1 = *(const short8*)(xp + 512 + lane * 8);

      // ================= ntile 0 =================
      i32x4 aR[2], aZ[2], aN[2];
#pragma unroll
      for (int nf = 0; nf < 2; ++nf){
        aR[nf] = (i32x4){0,0,0,0};
        aZ[nf] = (i32x4){0,0,0,0};
        aN[nf] = (i32x4){0,0,0,0};
      }
      CONS(a, 0)  WLD(a, FPTR(wkl, 2))
      CONS(b, 1)  WLD(b, FPTR(wkl, 3))
      CONS(a, 2)  WLD(a, FPTR(wkl, 4))
      CONS(b, 3)  WLD(b, FPTR(wkl, 5))
      CONS(a, 4)  WLD(a, FPTR(wkl, 6))
      CONS(b, 5)  WLD(b, FPTR(wkl, 7))
      CONS(a, 6)  WLD(a, FPTR(wkl, 8))
      CONS(b, 7)  WLD(b, FPTR(wkl, 9))

      {
        // gi + gates for ntile 0
        short8 wiR = *(const short8*)(wil);
        short8 wiZ = *(const short8*)(wil + 512);
        short8 wiN = *(const short8*)(wil + 1024);
        const f32x4 vR4  = *(const f32x4*)&sBrz[l * 1024 + colv0];
        const f32x4 vZ4  = *(const f32x4*)&sBrz[l * 1024 + 512 + colv0];
        const f32x4 vNi4 = *(const f32x4*)&sBni[l * 512 + colv0];
        const f32x4 vNh4 = *(const f32x4*)&sBnh[l * 512 + colv0];
        const f32x4 kR4  = *(const f32x4*)&sK[l * 1536 + colv0];
        const f32x4 kZ4  = *(const f32x4*)&sK[l * 1536 + 512 + colv0];
        const f32x4 kN4  = *(const f32x4*)&sK[l * 1536 + 1024 + colv0];
        f32x4 gR[2], gZ[2], gN[2];
        gR[0] = vR4;  gR[1] = vR4;
        gZ[0] = vZ4;  gZ[1] = vZ4;
        gN[0] = vNi4; gN[1] = vNi4;
        gR[0] = MFMA(wiR, xb0, gR[0]);  gR[1] = MFMA(wiR, xb1, gR[1]);
        gZ[0] = MFMA(wiZ, xb0, gZ[0]);  gZ[1] = MFMA(wiZ, xb1, gZ[1]);
        gN[0] = MFMA(wiN, xb0, gN[0]);  gN[1] = MFMA(wiN, xb1, gN[1]);
#pragma unroll
        for (int nf = 0; nf < 2; ++nf){
          unsigned pk = 0;
#pragma unroll
          for (int qq = 0; qq < 4; ++qq){
            float rp = gR[nf][qq] + (float)aR[nf][qq] * kR4[qq];
            float zp = gZ[nf][qq] + (float)aZ[nf][qq] * kZ4[qq];
            float r  = frcp(1.f + fexp2(-rp));
            float z  = frcp(1.f + fexp2(-zp));
            float an = gN[nf][qq] + r * ((float)aN[nf][qq] * kN4[qq] + vNh4[qq]);
            float n  = fmaf(-2.f, frcp(1.f + fexp2(an)), 1.f);
            float hn = fmaf(z, hreg[0][nf][qq] - n, n);
            hreg[0][nf][qq] = hn;
            int hq = (int)rintf(hn * 127.f);
            pk |= ((unsigned)(hq & 0xFF)) << (qq * 8);
          }
          int brow = nf * 16 + l15;
          *(unsigned*)(hb8n + brow * H8STR + colv0) = pk;
        }
      }

      // ================= ntile 1 =================
#pragma unroll
      for (int nf = 0; nf < 2; ++nf){
        aR[nf] = (i32x4){0,0,0,0};
        aZ[nf] = (i32x4){0,0,0,0};
        aN[nf] = (i32x4){0,0,0,0};
      }
      // next step's layer pointer for cross-step prefetch of seq 0,1
      const unsigned char* wkn = wklB + (size_t)(l == NL - 1 ? 0 : l + 1) * WKL_STRIDE;
      CONS(a, 8)   WLD(a, FPTR(wkl, 10))
      CONS(b, 9)   WLD(b, FPTR(wkl, 11))
      CONS(a, 10)  WLD(a, FPTR(wkl, 12))
      CONS(b, 11)  WLD(b, FPTR(wkl, 13))
      CONS(a, 12)  WLD(a, FPTR(wkl, 14))
      CONS(b, 13)  WLD(b, FPTR(wkl, 15))
      CONS(a, 14)  WLD(a, FPTR(wkn, 0))
      CONS(b, 15)  WLD(b, FPTR(wkn, 1))

      {
        // gi + gates for ntile 1
        const unsigned short* wi1 = wil + 3 * 512;
        short8 wiR = *(const short8*)(wi1);
        short8 wiZ = *(const short8*)(wi1 + 512);
        short8 wiN = *(const short8*)(wi1 + 1024);
        const f32x4 vR4  = *(const f32x4*)&sBrz[l * 1024 + colv1];
        const f32x4 vZ4  = *(const f32x4*)&sBrz[l * 1024 + 512 + colv1];
        const f32x4 vNi4 = *(const f32x4*)&sBni[l * 512 + colv1];
        const f32x4 vNh4 = *(const f32x4*)&sBnh[l * 512 + colv1];
        const f32x4 kR4  = *(const f32x4*)&sK[l * 1536 + colv1];
        const f32x4 kZ4  = *(const f32x4*)&sK[l * 1536 + 512 + colv1];
        const f32x4 kN4  = *(const f32x4*)&sK[l * 1536 + 1024 + colv1];
        f32x4 gR[2], gZ[2], gN[2];
        gR[0] = vR4;  gR[1] = vR4;
        gZ[0] = vZ4;  gZ[1] = vZ4;
        gN[0] = vNi4; gN[1] = vNi4;
        gR[0] = MFMA(wiR, xb0, gR[0]);  gR[1] = MFMA(wiR, xb1, gR[1]);
        gZ[0] = MFMA(wiZ, xb0, gZ[0]);  gZ[1] = MFMA(wiZ, xb1, gZ[1]);
        gN[0] = MFMA(wiN, xb0, gN[0]);  gN[1] = MFMA(wiN, xb1, gN[1]);
#pragma unroll
        for (int nf = 0; nf < 2; ++nf){
          unsigned pk = 0;
#pragma unroll
          for (int qq = 0; qq < 4; ++qq){
            float rp = gR[nf][qq] + (float)aR[nf][qq] * kR4[qq];
            float zp = gZ[nf][qq] + (float)aZ[nf][qq] * kZ4[qq];
            float r  = frcp(1.f + fexp2(-rp));
            float z  = frcp(1.f + fexp2(-zp));
            float an = gN[nf][qq] + r * ((float)aN[nf][qq] * kN4[qq] + vNh4[qq]);
            float n  = fmaf(-2.f, frcp(1.f + fexp2(an)), 1.f);
            float hn = fmaf(z, hreg[1][nf][qq] - n, n);
            hreg[1][nf][qq] = hn;
            int hq = (int)rintf(hn * 127.f);
            pk |= ((unsigned)(hq & 0xFF)) << (qq * 8);
          }
          int brow = nf * 16 + l15;
          *(unsigned*)(hb8n + brow * H8STR + colv1) = pk;
        }
      }

      // stage x(t+1) before the end-of-step barrier
      if (l == NL - 1 && t < S_LEN - 1){
        float xv = xvalid ? x[xbase + (size_t)(t + 1) * IN_D] : 0.f;
        xpack[(t + 1) & 1][tid] = f2bf(xv);
      }

      if (!last) __syncthreads();   // the ONLY barrier per cell-layer
      cur ^= 1;
    }
  }
#undef WLD
#undef CONS
#undef FPTR

  // epilogue: lane holds 4 consecutive out-cols per (ntile, batch-frag) -> dwordx4
#pragma unroll
  for (int nt = 0; nt < 2; ++nt)
#pragma unroll
    for (int nf = 0; nf < 2; ++nf){
      f32x4 v = { hreg[nt][nf][0], hreg[nt][nf][1], hreg[nt][nf][2], hreg[nt][nf][3] };
      int brow = nf * 16 + l15;
      out[((size_t)(b0 + brow)) * 512 + (nt ? colv1 : colv0) + 0] = v[0];
      out[((size_t)(b0 + brow)) * 512 + (nt ? colv1 : colv0) + 1] = v[1];
      out[((size_t)(b0 + brow)) * 512 + (nt ? colv1 : colv0) + 2] = v[2];
      out[((size_t)(b0 + brow)) * 512 + (nt ? colv1 : colv0) + 3] = v[3];
    }

  if ((size_t)x == 2) out[0] = (float)pad[tid];   // pad liveness (never true)
}

extern "C" void kernel_launch(void* const* d_in, const int* in_sizes, int n_in,
                              void* d_out, int out_size, void* d_ws, size_t ws_size,
                              hipStream_t stream){
  const float* x   = (const float*)d_in[0];
  const float* Wih = (const float*)d_in[1];
  const float* Whh = (const float*)d_in[2];
  const float* bih = (const float*)d_in[3];
  const float* bhh = (const float*)d_in[4];

  unsigned char* ws = (unsigned char*)d_ws;
  unsigned char*  Wp8  = (unsigned char*)(ws + OFF_WI8);
  unsigned short* Wip  = (unsigned short*)(ws + OFF_WIH);
  float*          sw   = (float*)(ws + OFF_SW);
  float*          swi  = (float*)(ws + OFF_SWI);

  prep_scale<<<1152, 256, 0, stream>>>(Whh, sw, swi);
  prep_wi8  <<< 576, 256, 0, stream>>>(Whh, swi, Wp8);
  prep_wih  <<<  72, 256, 0, stream>>>(Wih, Wip);
  gru_main  <<< 128, 1024, 0, stream>>>(x, Wp8, Wip, bih, bhh, sw, (float*)d_out);
}